// Round 3
// baseline (524.671 us; speedup 1.0000x reference)
//
#include <hip/hip_runtime.h>

// Problem constants (from reference setup_inputs)
constexpr int MP  = 10242;  // coarse vertices (output rows)
constexpr int B   = 16;     // batch
constexpr int M   = 40962;  // fine vertices
constexpr int F   = 128;    // features
constexpr int CAP = 32;     // ELL capacity per row; counts ~Poisson(4), P(>32) ~ 1e-18

typedef float f32x4 __attribute__((ext_vector_type(4)));

// ---------------------------------------------------------------------------
// Build ELL + mark used columns. counts[] doubles as the insertion cursor.
__global__ void build_ell_kernel(const int* __restrict__ rows,
                                 const int* __restrict__ cols,
                                 const float* __restrict__ vals,
                                 int* __restrict__ counts,        // [MP], zeroed
                                 int2* __restrict__ ell,          // [MP*CAP]
                                 unsigned char* __restrict__ used,// [M], zeroed (null in fallback)
                                 int nnz) {
    int k = blockIdx.x * blockDim.x + threadIdx.x;
    if (k < nnz) {
        int p = rows[k];
        int c = cols[k];
        if (used) used[c] = 1;
        int slot = atomicAdd(&counts[p], 1);
        if (slot < CAP) {                 // safety clamp; never triggers at Poisson(4)
            ell[p * CAP + slot] = make_int2(c, __float_as_int(vals[k]));
        }
    }
}

// ---------------------------------------------------------------------------
// Batch-transpose used columns: x[B][M][F] -> xt[M][B][F].
// One wave per fine vertex m; skips unused m (wave-uniform early exit).
// Reads: 16 sequential 512B streams; writes: 8KB contiguous per m.
__global__ __launch_bounds__(256)
void transpose_kernel(const float4* __restrict__ x,
                      const unsigned char* __restrict__ used,
                      float4* __restrict__ xt) {
    int m = blockIdx.x * 4 + (threadIdx.x >> 6);
    if (m >= M || !used[m]) return;
    int lane = threadIdx.x & 63;
    // iteration i handles batch b = 2*i + (lane>>5), float4-lane l = lane&31
    const float4* src = x + ((size_t)(lane >> 5) * M + (size_t)m) * 32 + (lane & 31);
    float4*       dst = xt + (size_t)m * 512 + lane;
    f32x4 v[8];
#pragma unroll
    for (int i = 0; i < 8; ++i)   // 8 independent 1KB loads in flight
        v[i] = __builtin_nontemporal_load((const f32x4*)(src + (size_t)(2 * i) * M * 32));
#pragma unroll
    for (int i = 0; i < 8; ++i)   // plain stores: keep xt hot in L2/L3 for pool
        dst[i * 64] = *(float4*)&v[i];
}

// ---------------------------------------------------------------------------
// Pool from transposed layout: block per coarse vertex p. Each entry's read
// is one contiguous 8KB block (xt[c][*][*]), fully coalesced over 256 threads.
// Thread t accumulates slots (b=t>>5, l=t&31) and (b+8, l).
__global__ __launch_bounds__(256)
void pool_xt_kernel(const float4* __restrict__ xt,
                    const int* __restrict__ counts,
                    const int2* __restrict__ ell,
                    float4* __restrict__ out) {
    const int p = blockIdx.x;
    const int t = threadIdx.x;
    int n = counts[p];
    n = n < CAP ? n : CAP;
    const int2* pe = ell + p * CAP;     // block-uniform -> scalar loads

    f32x4 acc0 = {0.f, 0.f, 0.f, 0.f}, acc1 = {0.f, 0.f, 0.f, 0.f};
    int j = 0;
    for (; j + 2 <= n; j += 2) {
        int2 e0 = pe[j], e1 = pe[j + 1];
        const f32x4* r0 = (const f32x4*)(xt + (size_t)e0.x * 512);
        const f32x4* r1 = (const f32x4*)(xt + (size_t)e1.x * 512);
        f32x4 a0 = r0[t], a1 = r0[t + 256];   // 4 x 4KB block loads in flight
        f32x4 b0 = r1[t], b1 = r1[t + 256];
        float v0 = __int_as_float(e0.y), v1 = __int_as_float(e1.y);
        acc0 += v0 * a0; acc1 += v0 * a1;
        acc0 += v1 * b0; acc1 += v1 * b1;
    }
    if (j < n) {
        int2 e = pe[j];
        const f32x4* r = (const f32x4*)(xt + (size_t)e.x * 512);
        float v = __int_as_float(e.y);
        acc0 += v * r[t]; acc1 += v * r[t + 256];
    }
    int b0i = t >> 5, l = t & 31;
    f32x4* o0 = (f32x4*)(out + ((size_t)b0i * MP + p) * 32 + l);
    f32x4* o1 = (f32x4*)(out + ((size_t)(b0i + 8) * MP + p) * 32 + l);
    __builtin_nontemporal_store(acc0, o0);   // out never re-read
    __builtin_nontemporal_store(acc1, o1);
}

// ---------------------------------------------------------------------------
// Fallback pool (direct gather from x) — the verified R1 path, used only if
// ws_size can't hold the transposed copy.
__global__ __launch_bounds__(256)
void pool_direct_kernel(const float4* __restrict__ x,
                        const int* __restrict__ counts,
                        const int2* __restrict__ ell,
                        float4* __restrict__ out) {
    const int p    = blockIdx.x;
    const int q    = threadIdx.x >> 6;
    const int lane = threadIdx.x & 63;
    const int bA   = (q << 1) | (lane >> 5);
    const int bB   = bA + 8;
    const int l    = lane & 31;

    int n = counts[p];
    n = n < CAP ? n : CAP;
    const int2* pe = ell + p * CAP;
    const float4* xA = x + (size_t)bA * (M * (F / 4));
    const float4* xB = x + (size_t)bB * (M * (F / 4));

    f32x4 accA = {0.f, 0.f, 0.f, 0.f}, accB = {0.f, 0.f, 0.f, 0.f};
    for (int j = 0; j < n; ++j) {
        int2 e = pe[j];
        float v = __int_as_float(e.y);
        f32x4 a = *(const f32x4*)&xA[(size_t)e.x * 32 + l];
        f32x4 c = *(const f32x4*)&xB[(size_t)e.x * 32 + l];
        accA += v * a;
        accB += v * c;
    }
    f32x4* oA = (f32x4*)(out + ((size_t)bA * MP + p) * 32 + l);
    f32x4* oB = (f32x4*)(out + ((size_t)bB * MP + p) * 32 + l);
    __builtin_nontemporal_store(accA, oA);
    __builtin_nontemporal_store(accB, oB);
}

// ---------------------------------------------------------------------------
extern "C" void kernel_launch(void* const* d_in, const int* in_sizes, int n_in,
                              void* d_out, int out_size, void* d_ws, size_t ws_size,
                              hipStream_t stream) {
    const float* x    = (const float*)d_in[0];
    const int*   rows = (const int*)d_in[1];
    const int*   cols = (const int*)d_in[2];
    const float* vals = (const float*)d_in[3];
    float* out = (float*)d_out;
    const int nnz = in_sizes[1];
    const int nb  = (nnz + 255) / 256;

    // Big-path workspace layout: xt[M*B*F f32] | counts[MP] | ell[MP*CAP int2] | used[M]
    size_t xt_bytes   = (size_t)M * B * F * sizeof(float);     // 335,560,704 (8-aligned)
    size_t counts_off = xt_bytes;
    size_t ell_off    = counts_off + (size_t)MP * sizeof(int); // stays 8-aligned
    size_t used_off   = ell_off + (size_t)MP * CAP * sizeof(int2);
    size_t needed     = used_off + (size_t)M;

    if (ws_size >= needed) {
        float* xt              = (float*)d_ws;
        int*   counts          = (int*)((char*)d_ws + counts_off);
        int2*  ell             = (int2*)((char*)d_ws + ell_off);
        unsigned char* used    = (unsigned char*)((char*)d_ws + used_off);

        hipMemsetAsync(counts, 0, MP * sizeof(int), stream);
        hipMemsetAsync(used, 0, M, stream);

        build_ell_kernel<<<nb, 256, 0, stream>>>(rows, cols, vals, counts, ell,
                                                 used, nnz);
        transpose_kernel<<<(M + 3) / 4, 256, 0, stream>>>((const float4*)x, used,
                                                          (float4*)xt);
        pool_xt_kernel<<<MP, 256, 0, stream>>>((const float4*)xt, counts, ell,
                                               (float4*)out);
    } else {
        // Fallback: verified R1 direct-gather path (needs ~2.7 MB)
        int*  counts = (int*)d_ws;
        int2* ell    = (int2*)(counts + MP);
        hipMemsetAsync(counts, 0, MP * sizeof(int), stream);
        build_ell_kernel<<<nb, 256, 0, stream>>>(rows, cols, vals, counts, ell,
                                                 (unsigned char*)nullptr, nnz);
        pool_direct_kernel<<<MP, 256, 0, stream>>>((const float4*)x, counts, ell,
                                                   (float4*)out);
    }
}